// Round 2
// baseline (22052.397 us; speedup 1.0000x reference)
//
#include <hip/hip_runtime.h>

typedef _Float16 f16;
typedef _Float16 f16x8 __attribute__((ext_vector_type(8)));
typedef _Float16 f16x4v __attribute__((ext_vector_type(4)));
typedef float f32x4 __attribute__((ext_vector_type(4)));

#define T_SEQ 512
#define NBATCH 64
#define HD 1024
#define GD 3072
#define TCH 64  // timestep chunk (bounds gates buffer to 50MB)

typedef unsigned int u32g __attribute__((address_space(1)));
typedef unsigned int u32l __attribute__((address_space(3)));

// async global->LDS, 16B per lane; lds base must be wave-uniform (guide §5)
__device__ __forceinline__ void async16(void* lds, const void* g) {
  __builtin_amdgcn_global_load_lds((const u32g*)g, (u32l*)lds, 16, 0, 0);
}

// ---------------- prep: f32 -> f16 hi/lo split ----------------
__global__ void k_split(const float* __restrict__ s, f16* __restrict__ hi,
                        f16* __restrict__ lo, int n) {
  int i = (blockIdx.x * blockDim.x + threadIdx.x) * 4;
  int stride = gridDim.x * blockDim.x * 4;
  for (; i < n; i += stride) {
    float4 v = *(const float4*)(s + i);
    f16 a = (f16)v.x, b = (f16)v.y, c = (f16)v.z, d = (f16)v.w;
    f16x4v hv = {a, b, c, d};
    f16x4v lv = {(f16)(v.x - (float)a), (f16)(v.y - (float)b),
                 (f16)(v.z - (float)c), (f16)(v.w - (float)d)};
    *(f16x4v*)(hi + i) = hv;
    *(f16x4v*)(lo + i) = lv;
  }
}

__global__ void k_hinit(const float* __restrict__ H0, float* __restrict__ h32,
                        f16* __restrict__ hhi, f16* __restrict__ hlo) {
  int i = blockIdx.x * blockDim.x + threadIdx.x;  // 65536 threads
  float v = H0[i];
  h32[i] = v;
  f16 h = (f16)v;
  hhi[i] = h;
  hlo[i] = (f16)(v - (float)h);
}

// ---------------- gates_x GEMM: C[M,3072] = X·Wih^T + b ----------------
// f16 split 3-term: hi*hi + hi*lo + lo*hi. 128x128 tile, BK=32, 4 waves 2x2.
__global__ __launch_bounds__(256)
void gemm_gates(const f16* __restrict__ Ahi, const f16* __restrict__ Alo,
                const f16* __restrict__ Bhi, const f16* __restrict__ Blo,
                const float* __restrict__ bias, float* __restrict__ C, int M) {
  __shared__ f16 lds[4][128 * 32];  // planes: Ahi,Alo,Bhi,Blo; 8KB each
  const int tid = threadIdx.x;
  const int wid = tid >> 6, lane = tid & 63;
  const int nb = blockIdx.x % 24, mb = blockIdx.x / 24;
  const int row0 = mb * 128, col0 = nb * 128;
  const int wr = wid >> 1, wc = wid & 1;
  const int fr = lane & 15, fg = lane >> 4;

  f32x4 zero = {0.f, 0.f, 0.f, 0.f};
  f32x4 acc[4][4];
  #pragma unroll
  for (int i = 0; i < 4; ++i)
    #pragma unroll
    for (int j = 0; j < 4; ++j) acc[i][j] = zero;

  // wave w stages plane w (no runtime-indexed ptr array -> no scratch)
  const f16* sp0 = (wid == 0) ? (Ahi + (long)row0 * HD)
                 : (wid == 1) ? (Alo + (long)row0 * HD)
                 : (wid == 2) ? (Bhi + (long)col0 * HD)
                              : (Blo + (long)col0 * HD);
  char* dstbase = (char*)&lds[wid][0];

  for (int kt = 0; kt < HD / 32; ++kt) {
    __syncthreads();  // protect LDS from previous iteration's readers
    #pragma unroll
    for (int is = 0; is < 8; ++is) {
      int g = is * 64 + lane;        // 16B granule id within plane
      int r = g >> 2, gc = g & 3;    // row, granule-in-row (64B rows)
      // XOR swizzle f(r)=(r&3)<<4: stays coalesced, fixes read conflicts
      const char* sp = (const char*)sp0 + (long)r * 2048 + kt * 64 +
                       ((gc << 4) ^ ((r & 3) << 4));
      async16(dstbase + is * 1024, sp);
    }
    __syncthreads();  // implicit vmcnt(0) drains global_load_lds

    f16x8 ah[4], al[4], bh[4], bl[4];
    #pragma unroll
    for (int i = 0; i < 4; ++i) {
      int ar = wr * 64 + i * 16 + fr;
      int aoff = ar * 64 + ((fg << 4) ^ ((ar & 3) << 4));
      ah[i] = *(const f16x8*)((const char*)&lds[0][0] + aoff);
      al[i] = *(const f16x8*)((const char*)&lds[1][0] + aoff);
      int br = wc * 64 + i * 16 + fr;
      int boff = br * 64 + ((fg << 4) ^ ((br & 3) << 4));
      bh[i] = *(const f16x8*)((const char*)&lds[2][0] + boff);
      bl[i] = *(const f16x8*)((const char*)&lds[3][0] + boff);
    }
    #pragma unroll
    for (int i = 0; i < 4; ++i)
      #pragma unroll
      for (int j = 0; j < 4; ++j) {
        acc[i][j] = __builtin_amdgcn_mfma_f32_16x16x32_f16(ah[i], bh[j], acc[i][j], 0, 0, 0);
        acc[i][j] = __builtin_amdgcn_mfma_f32_16x16x32_f16(ah[i], bl[j], acc[i][j], 0, 0, 0);
        acc[i][j] = __builtin_amdgcn_mfma_f32_16x16x32_f16(al[i], bh[j], acc[i][j], 0, 0, 0);
      }
  }
  // epilogue: D layout col=lane&15, row=(lane>>4)*4+reg (m89-verified)
  #pragma unroll
  for (int i = 0; i < 4; ++i) {
    int gm = row0 + wr * 64 + i * 16 + fg * 4;
    #pragma unroll
    for (int j = 0; j < 4; ++j) {
      int gn = col0 + wc * 64 + j * 16 + fr;
      float bv = bias[gn];
      #pragma unroll
      for (int r = 0; r < 4; ++r)
        C[(long)(gm + r) * GD + gn] = acc[i][j][r] + bv;
    }
  }
}

// ---------------- persistent recurrence (plain launch + manual barrier) ----
// 256 WGs = 4 batch-groups(16) x 64 unit-groups(16). Per WG: 48 W_hh rows
// (r/z/n blocks) resident in VGPRs as MFMA A-frags (hi+lo = 192 regs).
// Per step: stage h-pair group (64KB) -> LDS, K-split GEMM over 4 waves,
// LDS partial reduce, gate math, write h_new, per-bg 64-block barrier.
// Barrier domain = one batch-group (only same-bg blocks produce the h this
// block consumes). bg=bid&3 with XCD=bid%8 clusters each domain on 2 XCDs.
__global__ __launch_bounds__(256, 1)
void gru_recur(const f16* __restrict__ Whi, const f16* __restrict__ Wlo,
               const float* __restrict__ gates, const float* __restrict__ bhh,
               float* __restrict__ h32, f16* __restrict__ hhi, f16* __restrict__ hlo,
               f16* __restrict__ yhi, f16* __restrict__ ylo, float* __restrict__ yf,
               unsigned* __restrict__ bar, int gs0, int t0, int nsteps, int layer2) {
  __shared__ f16 hbuf[2][16 * 1024];    // hi/lo planes, 32KB each, XOR-swizzled
  __shared__ float part[4][3][64][4];   // per-wave partial D tiles, 12KB
  const int tid = threadIdx.x, wid = tid >> 6, lane = tid & 63;
  const int bid = blockIdx.x;
  const int bg = bid & 3, ug = bid >> 2;
  const int u0 = ug * 16;
  const int fr = lane & 15, fg = lane >> 4;

  // stationary W_hh fragments: wave wid owns k in [wid*256, wid*256+256)
  f16x8 whf[3][8], wlf[3][8];
  #pragma unroll
  for (int m = 0; m < 3; ++m) {
    long wrow = (long)(m * 1024 + u0 + fr) * HD;
    #pragma unroll
    for (int kc = 0; kc < 8; ++kc) {
      int k = wid * 256 + kc * 32 + fg * 8;
      whf[m][kc] = *(const f16x8*)(Whi + wrow + k);
      wlf[m][kc] = *(const f16x8*)(Wlo + wrow + k);
    }
  }
  const int ti = tid & 15, tb = tid >> 4;   // unit-in-group, batch-in-group
  const int ug_ = u0 + ti, bg_ = bg * 16 + tb;
  const float bh_r = bhh[ug_], bh_z = bhh[1024 + ug_], bh_n = bhh[2048 + ug_];
  const int lp = ((ti >> 2) << 4) | tb, rg = ti & 3;  // D-tile lane/reg for (ti,tb)

  for (int st = 0; st < nsteps; ++st) {
    const int t = t0 + st;
    const int pr = t & 1, pn = pr ^ 1;
    {
      const f16* s0 = hhi + pr * 65536 + bg * 16 * HD;
      const f16* s1 = hlo + pr * 65536 + bg * 16 * HD;
      #pragma unroll
      for (int p = 0; p < 2; ++p) {
        const char* sb = (const char*)(p ? s1 : s0);
        char* db = (char*)&hbuf[p][0];
        #pragma unroll
        for (int is = 0; is < 8; ++is) {
          int g = (wid * 8 + is) * 64 + lane;   // granule id (2048 per plane)
          int r = g >> 7, gc = g & 127;         // row (2KB rows), granule-in-row
          // pre-swizzled source, linear LDS dest (rule #21): f(r)=(r&7)<<4
          async16(db + (wid * 8 + is) * 1024,
                  sb + r * 2048 + ((gc << 4) ^ ((r & 7) << 4)));
        }
      }
    }
    __syncthreads();
    // scalar prefetch (consumed after k-loop; latency hidden under MFMAs)
    long grow = ((long)st * NBATCH + bg_) * GD;
    float gx_r = gates[grow + ug_];
    float gx_z = gates[grow + 1024 + ug_];
    float gx_n = gates[grow + 2048 + ug_];
    float hold = h32[pr * 65536 + bg_ * HD + ug_];

    f32x4 z4 = {0.f, 0.f, 0.f, 0.f};
    f32x4 acc0 = z4, acc1 = z4, acc2 = z4;
    #pragma unroll
    for (int kc = 0; kc < 8; ++kc) {
      int gi = (wid * 8 + kc) * 4 + fg;
      int off = fr * 2048 + ((gi << 4) ^ ((fr & 7) << 4));
      f16x8 hbh = *(const f16x8*)((const char*)&hbuf[0][0] + off);
      f16x8 hbl = *(const f16x8*)((const char*)&hbuf[1][0] + off);
      acc0 = __builtin_amdgcn_mfma_f32_16x16x32_f16(whf[0][kc], hbh, acc0, 0, 0, 0);
      acc1 = __builtin_amdgcn_mfma_f32_16x16x32_f16(whf[1][kc], hbh, acc1, 0, 0, 0);
      acc2 = __builtin_amdgcn_mfma_f32_16x16x32_f16(whf[2][kc], hbh, acc2, 0, 0, 0);
      acc0 = __builtin_amdgcn_mfma_f32_16x16x32_f16(whf[0][kc], hbl, acc0, 0, 0, 0);
      acc1 = __builtin_amdgcn_mfma_f32_16x16x32_f16(whf[1][kc], hbl, acc1, 0, 0, 0);
      acc2 = __builtin_amdgcn_mfma_f32_16x16x32_f16(whf[2][kc], hbl, acc2, 0, 0, 0);
      acc0 = __builtin_amdgcn_mfma_f32_16x16x32_f16(wlf[0][kc], hbh, acc0, 0, 0, 0);
      acc1 = __builtin_amdgcn_mfma_f32_16x16x32_f16(wlf[1][kc], hbh, acc1, 0, 0, 0);
      acc2 = __builtin_amdgcn_mfma_f32_16x16x32_f16(wlf[2][kc], hbh, acc2, 0, 0, 0);
    }
    *(f32x4*)&part[wid][0][lane][0] = acc0;
    *(f32x4*)&part[wid][1][lane][0] = acc1;
    *(f32x4*)&part[wid][2][lane][0] = acc2;
    __syncthreads();

    float ghr = 0.f, ghz = 0.f, ghn = 0.f;
    #pragma unroll
    for (int w = 0; w < 4; ++w) {
      ghr += part[w][0][lp][rg];
      ghz += part[w][1][lp][rg];
      ghn += part[w][2][lp][rg];
    }
    float r_ = 1.f / (1.f + __expf(-(gx_r + ghr + bh_r)));
    float z_ = 1.f / (1.f + __expf(-(gx_z + ghz + bh_z)));
    float n_ = tanhf(gx_n + r_ * (ghn + bh_n));
    float hnew = (1.f - z_) * n_ + z_ * hold;

    int hidx = bg_ * HD + ug_;
    h32[pn * 65536 + hidx] = hnew;
    f16 nh = (f16)hnew;
    f16 nl = (f16)(hnew - (float)nh);
    hhi[pn * 65536 + hidx] = nh;
    hlo[pn * 65536 + hidx] = nl;
    long oidx = ((long)t * NBATCH + bg_) * HD + ug_;
    if (layer2) {
      yf[oidx] = hnew;              // final output x
    } else {
      yhi[oidx] = nh;               // ys1 as f16 pair -> layer2 GEMM input
      ylo[oidx] = nl;
    }

    // ---- per-batch-group 64-block barrier (skip after last step) ----
    if (st != nsteps - 1) {
      __syncthreads();              // all waves' stores drained to L2 (vmcnt 0)
      if (tid == 0) {
        __threadfence();            // L2 -> coherent point (agent release)
        unsigned* c = bar + (unsigned)(gs0 + st) * 4 + bg;
        atomicAdd(c, 1u);
        int spin = 0;
        while (atomicAdd(c, 0u) < 64u) {   // RMW poll: coherent-point read
          __builtin_amdgcn_s_sleep(2);
          if (++spin > (1 << 24)) break;   // bailout: fail loud, not hang
        }
        __threadfence();            // acquire: invalidate stale lines
      }
      __syncthreads();
    }
  }
}

// ---------------- orchestration ----------------
extern "C" void kernel_launch(void* const* d_in, const int* in_sizes, int n_in,
                              void* d_out, int out_size, void* d_ws, size_t ws_size,
                              hipStream_t stream) {
  (void)in_sizes; (void)n_in; (void)out_size; (void)ws_size;
  const float* x_in = (const float*)d_in[0];
  const float* H0   = (const float*)d_in[1];
  const float* Wih  = (const float*)d_in[2];
  const float* Whh  = (const float*)d_in[3];
  const float* bih  = (const float*)d_in[4];
  const float* bhh  = (const float*)d_in[5];
  float* out = (float*)d_out;

  char* ws = (char*)d_ws;
  const long WPE = 2L * GD * HD;                 // 6,291,456 elems per plane
  const long XNE = (long)T_SEQ * NBATCH * HD;    // 33,554,432
  unsigned* bar = (unsigned*)ws;                 // [1024 steps][4 bg], 16KB
  f16* WihHi = (f16*)(ws + 16384);
  f16* WihLo = WihHi + WPE;
  f16* WhhHi = WihLo + WPE;
  f16* WhhLo = WhhHi + WPE;
  f16* Xhi   = WhhLo + WPE;
  f16* Xlo   = Xhi + XNE;
  float* gates = (float*)(Xlo + XNE);            // [TCH][64][3072] f32, reused
  float* h32 = gates + (long)TCH * NBATCH * GD;  // [2][64][1024]
  f16* hhi = (f16*)(h32 + 2 * NBATCH * HD);      // [2][64][1024]
  f16* hlo = hhi + 2 * NBATCH * HD;
  // total ws ~ 236 MB

  hipMemsetAsync(bar, 0, 1024 * 4 * sizeof(unsigned), stream);
  k_split<<<4096, 256, 0, stream>>>(x_in, Xhi, Xlo, (int)XNE);
  k_split<<<2048, 256, 0, stream>>>(Wih, WihHi, WihLo, (int)WPE);
  k_split<<<2048, 256, 0, stream>>>(Whh, WhhHi, WhhLo, (int)WPE);

  for (int l = 0; l < 2; ++l) {
    k_hinit<<<256, 256, 0, stream>>>(H0 + (long)l * NBATCH * HD, h32, hhi, hlo);
    const f16* wihhi = WihHi + (long)l * GD * HD;
    const f16* wihlo = WihLo + (long)l * GD * HD;
    const f16* whhhi = WhhHi + (long)l * GD * HD;
    const f16* whhlo = WhhLo + (long)l * GD * HD;
    const float* bihl = bih + (long)l * GD;
    const float* bhhl = bhh + (long)l * GD;
    for (int c = 0; c < T_SEQ / TCH; ++c) {
      const f16* axhi = Xhi + (long)c * TCH * NBATCH * HD;
      const f16* axlo = Xlo + (long)c * TCH * NBATCH * HD;
      gemm_gates<<<dim3(32 * 24), 256, 0, stream>>>(axhi, axlo, wihhi, wihlo,
                                                    bihl, gates, TCH * NBATCH);
      int gs0 = l * T_SEQ + c * TCH;
      int t0 = c * TCH;
      gru_recur<<<dim3(256), dim3(256), 0, stream>>>(
          whhhi, whhlo, gates, bhhl, h32, hhi, hlo,
          Xhi, Xlo, out, bar, gs0, t0, TCH, l);
    }
    // final h of this layer lives at parity 0 (512 steps, even)
    hipMemcpyAsync(out + XNE + (long)l * NBATCH * HD, h32,
                   NBATCH * HD * sizeof(float), hipMemcpyDeviceToDevice, stream);
  }
}